// Round 6
// baseline (1480.748 us; speedup 1.0000x reference)
//
#include <hip/hip_runtime.h>
#include <stdint.h>

#define T_STEPS 8192
#define LSEQ    8192
#define H       256
#define D       64
#define PSCALE  0.125f   // 1/sqrt(64)
#define CONV_EPS 4e-4f   // convergence tolerance on max|h_t - h_{t-1}|

// ---- DIAGNOSTIC MULTIPLIERS (round 6 only): make each suspect kernel's
// dispatch duration exceed the ~155us harness-fill floor so it appears in
// the rocprof top-5 table. Each rep recomputes/rewrites IDENTICAL values ->
// deterministic, correctness unchanged. dur = 4R + 16A + 8P + M.
#define RNN_REPS  4
#define ATTN_REPS 16
#define REPL_REPS 8

typedef _Float16 half2_t __attribute__((ext_vector_type(2)));

#if __has_builtin(__builtin_amdgcn_fdot2)
#define FDOT2(a, b, c) __builtin_amdgcn_fdot2((a), (b), (c), false)
#else
#define FDOT2(a, b, c) fmaf((float)(a).x, (float)(b).x, fmaf((float)(a).y, (float)(b).y, (c)))
#endif

// ---------------------------------------------------------------------------
// K1: LSTM recurrence, EXACT r3 implementation (best total: 327us), wrapped
// in RNN_REPS full restarts from h0 (identical trajectory each rep).
// ---------------------------------------------------------------------------
__global__ __launch_bounds__(512, 2) void rnn_k(
    const float* __restrict__ enc, const float* __restrict__ W_ih,
    const float* __restrict__ b_ih, const float* __restrict__ b_hh,
    float* __restrict__ hs_out, float* __restrict__ hstar, int* __restrict__ nw_out)
{
    const int tid = threadIdx.x;
    const int j  = tid >> 1;          // hidden element [0,256)
    const int kc = tid & 1;           // K-chunk: cols [128*kc, 128*kc+128)

    half2_t wi[64], wg[64], wo[64];
    {
        const float* Wi = W_ih + (size_t)j * H + 128 * kc;
        const float* Wg = W_ih + (size_t)(512 + j) * H + 128 * kc;
        const float* Wo = W_ih + (size_t)(768 + j) * H + 128 * kc;
#pragma unroll
        for (int p = 0; p < 64; ++p) {
            half2_t a; a.x = (_Float16)Wi[2 * p]; a.y = (_Float16)Wi[2 * p + 1]; wi[p] = a;
            half2_t b; b.x = (_Float16)Wg[2 * p]; b.y = (_Float16)Wg[2 * p + 1]; wg[p] = b;
            half2_t c; c.x = (_Float16)Wo[2 * p]; c.y = (_Float16)Wo[2 * p + 1]; wo[p] = c;
        }
    }
    const float bi = b_ih[j] + b_hh[j];
    const float bg = b_ih[512 + j] + b_hh[512 + j];
    const float bo = b_ih[768 + j] + b_hh[768 + j];

    __shared__ half2_t hp[H / 2];     // h_{t-1} packed f16x2, broadcast-read

    int nw = T_STEPS;
    float hlast = 0.f;

    for (int rep = 0; rep < RNN_REPS; ++rep) {
        float hcur = enc[(size_t)(LSEQ - 1) * H + j];   // h0 = enc[-1]
        {
            float hnext = __shfl_xor(hcur, 2);          // pack partner h_{j^1}
            if ((tid & 3) == 0) { half2_t p; p.x = (_Float16)hcur; p.y = (_Float16)hnext; hp[tid >> 2] = p; }
        }
        __syncthreads();

        nw = T_STEPS;
        int streak = 0;
        for (int t = 1; t <= T_STEPS; ++t) {
            float ai = 0.f, ag = 0.f, ao = 0.f;
            const uint4* hp4 = (const uint4*)hp;        // 16 uint4 per K-chunk
#pragma unroll
            for (int q = 0; q < 16; ++q) {
                uint4 u = hp4[kc * 16 + q];
                half2_t h0 = __builtin_bit_cast(half2_t, u.x);
                half2_t h1 = __builtin_bit_cast(half2_t, u.y);
                half2_t h2 = __builtin_bit_cast(half2_t, u.z);
                half2_t h3 = __builtin_bit_cast(half2_t, u.w);
                ai = FDOT2(wi[4 * q + 0], h0, ai); ag = FDOT2(wg[4 * q + 0], h0, ag); ao = FDOT2(wo[4 * q + 0], h0, ao);
                ai = FDOT2(wi[4 * q + 1], h1, ai); ag = FDOT2(wg[4 * q + 1], h1, ag); ao = FDOT2(wo[4 * q + 1], h1, ao);
                ai = FDOT2(wi[4 * q + 2], h2, ai); ag = FDOT2(wg[4 * q + 2], h2, ag); ao = FDOT2(wo[4 * q + 2], h2, ao);
                ai = FDOT2(wi[4 * q + 3], h3, ai); ag = FDOT2(wg[4 * q + 3], h3, ag); ao = FDOT2(wo[4 * q + 3], h3, ao);
            }
            ai += __shfl_xor(ai, 1); ag += __shfl_xor(ag, 1); ao += __shfl_xor(ao, 1);
            ai += bi; ag += bg; ao += bo;

            float si = 1.0f / (1.0f + __expf(-ai));
            float eg = __expf(-2.0f * ag); float tg = (1.0f - eg) / (1.0f + eg);
            float so = 1.0f / (1.0f + __expf(-ao));
            float c  = si * tg;
            float ec = __expf(-2.0f * c);  float tc = (1.0f - ec) / (1.0f + ec);
            float hn = so * tc;

            int moving = (kc == 0 && fabsf(hn - hcur) >= CONV_EPS) ? 1 : 0;
            int nmov = __syncthreads_count(moving);     // also guards hp reads

            hcur = hn;
            float hnext = __shfl_xor(hn, 2);
            if ((tid & 3) == 0) { half2_t p; p.x = (_Float16)hn; p.y = (_Float16)hnext; hp[tid >> 2] = p; }
            if (kc == 0) hs_out[(size_t)(t - 1) * H + j] = hn;
            __syncthreads();                            // publish new hp

            streak = (nmov == 0) ? streak + 1 : 0;
            if (streak >= 2) { nw = t; break; }
        }
        hlast = hcur;
        __syncthreads();   // hp quiesced before next rep re-inits it
    }
    if (kc == 0) hstar[j] = hlast;
    if (tid == 0) nw_out[0] = nw;
}

// K2: fill hs[nw..T) with the fixed point h*   (exact r3 form)
__global__ __launch_bounds__(256) void fill_hs_k(
    float* __restrict__ hs_out, const float* __restrict__ hstar, const int* __restrict__ nw_p)
{
    int r = blockIdx.x;
    int nw = nw_p[0];
    if (r >= nw) hs_out[(size_t)r * H + threadIdx.x] = hstar[threadIdx.x];
}

// K3: out[r,d] = bias[d] + dot(in[r,:], W[d,:])   (exact r3 form)
__global__ __launch_bounds__(256) void proj_k(
    const float* __restrict__ in, const float* __restrict__ W,
    const float* __restrict__ bias, float* __restrict__ out)
{
    int idx = blockIdx.x * 256 + threadIdx.x;  // r*64 + d
    int r = idx >> 6, d = idx & 63;
    const float4* a4 = (const float4*)(in + (size_t)r * H);
    const float4* w4 = (const float4*)(W + (size_t)d * H);
    float s = 0.f;
#pragma unroll
    for (int k = 0; k < 64; ++k) {
        float4 a = a4[k], w = w4[k];
        s = fmaf(a.x, w.x, fmaf(a.y, w.y, fmaf(a.z, w.z, fmaf(a.w, w.w, s))));
    }
    out[idx] = bias[d] + s;
}

// K4: exact r3 form (block r owns row r, early return), x ATTN_REPS.
__global__ __launch_bounds__(256) void attn_k(
    const float* __restrict__ Qp, const float* __restrict__ Kp,
    const int* __restrict__ nw_p, float* __restrict__ out)
{
    const int r = blockIdx.x;
    const int nw = nw_p[0];
    if (r >= nw) return;
    const int tid = threadIdx.x;

    __shared__ float srow[LSEQ];     // 32 KB
    __shared__ float4 q4s[16];
    __shared__ float red[4];

    for (int rep = 0; rep < ATTN_REPS; ++rep) {
        if (tid < 16) q4s[tid] = ((const float4*)(Qp + (size_t)r * D))[tid];
        __syncthreads();             // also isolates prior rep's srow reads
        float4 qr[16];
#pragma unroll
        for (int k = 0; k < 16; ++k) qr[k] = q4s[k];

        for (int l = tid; l < LSEQ; l += 256) {
            const float4* k4 = (const float4*)(Kp + (size_t)l * D);
            float s = 0.f;
#pragma unroll
            for (int k = 0; k < 16; ++k) {
                float4 kv = k4[k];
                s = fmaf(kv.x, qr[k].x, fmaf(kv.y, qr[k].y, fmaf(kv.z, qr[k].z, fmaf(kv.w, qr[k].w, s))));
            }
            srow[l] = s * PSCALE;
        }
        __syncthreads();

        float m = -3.4e38f;
        for (int l = tid; l < LSEQ; l += 256) m = fmaxf(m, srow[l]);
#pragma unroll
        for (int off = 32; off; off >>= 1) m = fmaxf(m, __shfl_xor(m, off));
        if ((tid & 63) == 0) red[tid >> 6] = m;
        __syncthreads();
        m = fmaxf(fmaxf(red[0], red[1]), fmaxf(red[2], red[3]));
        __syncthreads();

        float s = 0.f;
        for (int l = tid; l < LSEQ; l += 256) { float e = __expf(srow[l] - m); srow[l] = e; s += e; }
#pragma unroll
        for (int off = 32; off; off >>= 1) s += __shfl_xor(s, off);
        if ((tid & 63) == 0) red[tid >> 6] = s;
        __syncthreads();
        s = red[0] + red[1] + red[2] + red[3];
        float inv = 1.0f / s;

        float4* o4 = (float4*)(out + (size_t)r * LSEQ);
        const float4* s4 = (const float4*)srow;
        for (int i = tid; i < LSEQ / 4; i += 256) {
            float4 v = s4[i];
            v.x *= inv; v.y *= inv; v.z *= inv; v.w *= inv;
            o4[i] = v;
        }
        __syncthreads();
    }
}

// K5: exact r3 form (block r copies row nw-1 -> row r), x REPL_REPS.
__global__ __launch_bounds__(256) void repl_k(
    float* __restrict__ out, const int* __restrict__ nw_p)
{
    int r = blockIdx.x;
    int nw = nw_p[0];
    if (r < nw) return;
    const float4* src = (const float4*)(out + (size_t)(nw - 1) * LSEQ);
    float4* dst = (float4*)(out + (size_t)r * LSEQ);
    for (int rep = 0; rep < REPL_REPS; ++rep)
        for (int i = threadIdx.x; i < LSEQ / 4; i += 256) dst[i] = src[i];
}

extern "C" void kernel_launch(void* const* d_in, const int* in_sizes, int n_in,
                              void* d_out, int out_size, void* d_ws, size_t ws_size,
                              hipStream_t stream)
{
    const float* enc  = (const float*)d_in[1];
    const float* W_ih = (const float*)d_in[2];
    // d_in[3] = W_hh multiplies the always-zero LSTM hidden state -> unused.
    const float* b_ih = (const float*)d_in[4];
    const float* b_hh = (const float*)d_in[5];
    const float* Wq   = (const float*)d_in[6];
    const float* bq   = (const float*)d_in[7];
    const float* Wk   = (const float*)d_in[8];
    const float* bk   = (const float*)d_in[9];

    float* out = (float*)d_out;                       // pointers: 8192*8192
    float* hs  = out + (size_t)T_STEPS * LSEQ;        // hs: 8192*256 (2nd output)

    // workspace layout (floats): [0] nw (int bits) | [64..320) h* | Kp | Qp
    float* wsf   = (float*)d_ws;
    int*   nw_p  = (int*)d_ws;
    float* hstar = wsf + 64;
    float* Kp    = wsf + 64 + 256;
    float* Qp    = Kp + (size_t)LSEQ * D;

    proj_k<<<(LSEQ * D) / 256, 256, 0, stream>>>(enc, Wk, bk, Kp);   // indep of rnn
    rnn_k<<<1, 512, 0, stream>>>(enc, W_ih, b_ih, b_hh, hs, hstar, nw_p);
    fill_hs_k<<<T_STEPS, 256, 0, stream>>>(hs, hstar, nw_p);
    proj_k<<<(T_STEPS * D) / 256, 256, 0, stream>>>(hs, Wq, bq, Qp);
    attn_k<<<T_STEPS, 256, 0, stream>>>(Qp, Kp, nw_p, out);
    repl_k<<<T_STEPS, 256, 0, stream>>>(out, nw_p);
}

// Round 7
// 264.732 us; speedup vs baseline: 5.5934x; 5.5934x over previous
//
#include <hip/hip_runtime.h>
#include <stdint.h>

#define T_STEPS 8192
#define LSEQ    8192
#define H       256
#define D       64
#define PSCALE  0.125f   // 1/sqrt(64)
#define CONV_EPS 4e-4f   // convergence tolerance (validated r2/r3/r6: nw ~ 7)
#define NCH     16       // score chunks per row
#define CHK     512      // keys per chunk (NCH*CHK == LSEQ)

typedef _Float16 half2_t __attribute__((ext_vector_type(2)));

#if __has_builtin(__builtin_amdgcn_fdot2)
#define FDOT2(a, b, c) __builtin_amdgcn_fdot2((a), (b), (c), false)
#else
#define FDOT2(a, b, c) fmaf((float)(a).x, (float)(b).x, fmaf((float)(a).y, (float)(b).y, (c)))
#endif

// ---------------------------------------------------------------------------
// K1: block 0 = LSTM recurrence (exact r3 structure; R~16us, nw~7).
//     blocks 1..512 = Kp projection (independent of the recurrence) fused in
//     so it rides the same dispatch.
// ---------------------------------------------------------------------------
__global__ __launch_bounds__(512, 2) void rnn_kp_k(
    const float* __restrict__ enc, const float* __restrict__ W_ih,
    const float* __restrict__ b_ih, const float* __restrict__ b_hh,
    const float* __restrict__ Wk, const float* __restrict__ bk,
    float* __restrict__ Kp,
    float* __restrict__ hs_out, float* __restrict__ hstar, int* __restrict__ nw_out)
{
    if (blockIdx.x != 0) {
        // ---- Kp: out[r,d] = bk[d] + dot(enc[r,:], Wk[d,:]) ----
        const int t = threadIdx.x;
        const int base = ((int)blockIdx.x - 1) * 1024;
#pragma unroll
        for (int half = 0; half < 2; ++half) {
            int idx = base + half * 512 + t;           // [0, 524288)
            int r = idx >> 6, d = idx & 63;
            const float4* a4 = (const float4*)(enc + (size_t)r * H);
            const float4* w4 = (const float4*)(Wk + (size_t)d * H);
            float s = 0.f;
#pragma unroll
            for (int k = 0; k < 64; ++k) {
                float4 a = a4[k], w = w4[k];
                s = fmaf(a.x, w.x, fmaf(a.y, w.y, fmaf(a.z, w.z, fmaf(a.w, w.w, s))));
            }
            Kp[idx] = bk[d] + s;
        }
        return;
    }

    // ---- block 0: the recurrence, exact r3 structure ----
    const int tid = threadIdx.x;
    const int j  = tid >> 1;          // hidden element [0,256)
    const int kc = tid & 1;           // K-chunk: cols [128*kc, 128*kc+128)

    half2_t wi[64], wg[64], wo[64];
    {
        const float4* Wi = (const float4*)(W_ih + (size_t)j * H + 128 * kc);
        const float4* Wg = (const float4*)(W_ih + (size_t)(512 + j) * H + 128 * kc);
        const float4* Wo = (const float4*)(W_ih + (size_t)(768 + j) * H + 128 * kc);
#pragma unroll
        for (int p = 0; p < 32; ++p) {
            float4 a = Wi[p], b = Wg[p], c = Wo[p];
            half2_t x;
            x.x = (_Float16)a.x; x.y = (_Float16)a.y; wi[2 * p] = x;
            x.x = (_Float16)a.z; x.y = (_Float16)a.w; wi[2 * p + 1] = x;
            x.x = (_Float16)b.x; x.y = (_Float16)b.y; wg[2 * p] = x;
            x.x = (_Float16)b.z; x.y = (_Float16)b.w; wg[2 * p + 1] = x;
            x.x = (_Float16)c.x; x.y = (_Float16)c.y; wo[2 * p] = x;
            x.x = (_Float16)c.z; x.y = (_Float16)c.w; wo[2 * p + 1] = x;
        }
    }
    const float bi = b_ih[j] + b_hh[j];
    const float bg = b_ih[512 + j] + b_hh[512 + j];
    const float bo = b_ih[768 + j] + b_hh[768 + j];

    __shared__ half2_t hp[H / 2];     // h_{t-1} packed f16x2, broadcast-read

    float hcur = enc[(size_t)(LSEQ - 1) * H + j];   // h0 = enc[-1]
    {
        float hnext = __shfl_xor(hcur, 2);          // pack partner h_{j^1}
        if ((tid & 3) == 0) { half2_t p; p.x = (_Float16)hcur; p.y = (_Float16)hnext; hp[tid >> 2] = p; }
    }
    __syncthreads();

    int nw = T_STEPS;
    int streak = 0;
    for (int t = 1; t <= T_STEPS; ++t) {
        float ai = 0.f, ag = 0.f, ao = 0.f;
        const uint4* hp4 = (const uint4*)hp;        // 16 uint4 per K-chunk
#pragma unroll
        for (int q = 0; q < 16; ++q) {
            uint4 u = hp4[kc * 16 + q];
            half2_t h0 = __builtin_bit_cast(half2_t, u.x);
            half2_t h1 = __builtin_bit_cast(half2_t, u.y);
            half2_t h2 = __builtin_bit_cast(half2_t, u.z);
            half2_t h3 = __builtin_bit_cast(half2_t, u.w);
            ai = FDOT2(wi[4 * q + 0], h0, ai); ag = FDOT2(wg[4 * q + 0], h0, ag); ao = FDOT2(wo[4 * q + 0], h0, ao);
            ai = FDOT2(wi[4 * q + 1], h1, ai); ag = FDOT2(wg[4 * q + 1], h1, ag); ao = FDOT2(wo[4 * q + 1], h1, ao);
            ai = FDOT2(wi[4 * q + 2], h2, ai); ag = FDOT2(wg[4 * q + 2], h2, ag); ao = FDOT2(wo[4 * q + 2], h2, ao);
            ai = FDOT2(wi[4 * q + 3], h3, ai); ag = FDOT2(wg[4 * q + 3], h3, ag); ao = FDOT2(wo[4 * q + 3], h3, ao);
        }
        ai += __shfl_xor(ai, 1); ag += __shfl_xor(ag, 1); ao += __shfl_xor(ao, 1);
        ai += bi; ag += bg; ao += bo;

        float si = 1.0f / (1.0f + __expf(-ai));
        float eg = __expf(-2.0f * ag); float tg = (1.0f - eg) / (1.0f + eg);
        float so = 1.0f / (1.0f + __expf(-ao));
        float c  = si * tg;
        float ec = __expf(-2.0f * c);  float tc = (1.0f - ec) / (1.0f + ec);
        float hn = so * tc;

        int moving = (kc == 0 && fabsf(hn - hcur) >= CONV_EPS) ? 1 : 0;
        int nmov = __syncthreads_count(moving);     // guards hp reads

        hcur = hn;
        float hnext = __shfl_xor(hn, 2);
        if ((tid & 3) == 0) { half2_t p; p.x = (_Float16)hn; p.y = (_Float16)hnext; hp[tid >> 2] = p; }
        if (kc == 0) hs_out[(size_t)(t - 1) * H + j] = hn;
        __syncthreads();                            // publish new hp

        streak = (nmov == 0) ? streak + 1 : 0;
        if (streak >= 2) { nw = t; break; }
    }
    if (kc == 0) hstar[j] = hcur;
    if (tid == 0) nw_out[0] = nw;
}

// ---------------------------------------------------------------------------
// K2: prep — Qp for rows < nw (attention only needs the distinct rows; Qp is
// scratch, not an output) + fill hs[nw..T) with h*.
// ---------------------------------------------------------------------------
__global__ __launch_bounds__(256) void prep_k(
    const float* __restrict__ hs, const float* __restrict__ Wq,
    const float* __restrict__ bq, float* __restrict__ Qp,
    const float* __restrict__ hstar, float* __restrict__ hs_out,
    const int* __restrict__ nw_p)
{
    const int nw = nw_p[0];
    const int tid = threadIdx.x;
    for (int idx = blockIdx.x * 256 + tid; idx < nw * 64; idx += gridDim.x * 256) {
        int r = idx >> 6, d = idx & 63;
        const float4* a4 = (const float4*)(hs + (size_t)r * H);
        const float4* w4 = (const float4*)(Wq + (size_t)d * H);
        float s = 0.f;
#pragma unroll
        for (int k = 0; k < 64; ++k) {
            float4 a = a4[k], w = w4[k];
            s = fmaf(a.x, w.x, fmaf(a.y, w.y, fmaf(a.z, w.z, fmaf(a.w, w.w, s))));
        }
        Qp[idx] = bq[d] + s;
    }
    for (int r = nw + blockIdx.x; r < T_STEPS; r += gridDim.x)
        hs_out[(size_t)r * H + tid] = hstar[tid];
}

// ---------------------------------------------------------------------------
// K3: attnA — chunked QK^T. Item (r,c): 512 scores -> ws, plus chunk max and
// chunk sum of exp(s - cmax). Persistent grid; fixed-order reductions.
// ---------------------------------------------------------------------------
__global__ __launch_bounds__(256) void attnA_k(
    const float* __restrict__ Qp, const float* __restrict__ Kp,
    const int* __restrict__ nw_p, int cap,
    float* __restrict__ scores, float* __restrict__ cmax, float* __restrict__ csum)
{
    const int na = min(nw_p[0], cap);
    const int tid = threadIdx.x;
    __shared__ float4 q4s[16];
    __shared__ float red[4];

    for (int it = blockIdx.x; it < na * NCH; it += gridDim.x) {
        const int r = it >> 4, c = it & (NCH - 1);
        if (tid < 16) q4s[tid] = ((const float4*)(Qp + (size_t)r * D))[tid];
        __syncthreads();
        float4 qr[16];
#pragma unroll
        for (int k = 0; k < 16; ++k) qr[k] = q4s[k];

        const int k0 = c * CHK + tid;         // and k0+256
        float s01[2];
#pragma unroll
        for (int h = 0; h < 2; ++h) {
            const float4* k4 = (const float4*)(Kp + (size_t)(k0 + 256 * h) * D);
            float s = 0.f;
#pragma unroll
            for (int k = 0; k < 16; ++k) {
                float4 kv = k4[k];
                s = fmaf(kv.x, qr[k].x, fmaf(kv.y, qr[k].y, fmaf(kv.z, qr[k].z, fmaf(kv.w, qr[k].w, s))));
            }
            s01[h] = s * PSCALE;
            scores[(size_t)r * LSEQ + k0 + 256 * h] = s01[h];
        }

        float m = fmaxf(s01[0], s01[1]);
#pragma unroll
        for (int off = 32; off; off >>= 1) m = fmaxf(m, __shfl_xor(m, off));
        if ((tid & 63) == 0) red[tid >> 6] = m;
        __syncthreads();
        m = fmaxf(fmaxf(red[0], red[1]), fmaxf(red[2], red[3]));
        __syncthreads();                       // red reuse guard

        float e = __expf(s01[0] - m) + __expf(s01[1] - m);
#pragma unroll
        for (int off = 32; off; off >>= 1) e += __shfl_xor(e, off);
        if ((tid & 63) == 0) red[tid >> 6] = e;
        __syncthreads();
        if (tid == 0) { cmax[it] = m; csum[it] = red[0] + red[1] + red[2] + red[3]; }
        __syncthreads();                       // red/q4s guard for next item
    }
}

// K4: attnB — exact log-sum-exp combine of the 16 chunk partials per row.
__global__ __launch_bounds__(64) void attnB_k(
    const int* __restrict__ nw_p, int cap,
    const float* __restrict__ cmax, const float* __restrict__ csum,
    float* __restrict__ rowm, float* __restrict__ rowinv)
{
    const int na = min(nw_p[0], cap);
    const int lane = threadIdx.x;
    for (int r = blockIdx.x; r < na; r += gridDim.x) {
        float cm = (lane < NCH) ? cmax[r * NCH + lane] : -3.4e38f;
        float m = cm;
#pragma unroll
        for (int off = 32; off; off >>= 1) m = fmaxf(m, __shfl_xor(m, off));
        float v = (lane < NCH) ? csum[r * NCH + lane] * __expf(cm - m) : 0.f;
#pragma unroll
        for (int off = 32; off; off >>= 1) v += __shfl_xor(v, off);
        if (lane == 0) { rowm[r] = m; rowinv[r] = 1.0f / v; }
    }
}

// K5: attnC — normalize + write the 32KB output row, chunked, persistent.
__global__ __launch_bounds__(256) void attnC_k(
    const int* __restrict__ nw_p, int cap,
    const float* __restrict__ scores, const float* __restrict__ rowm,
    const float* __restrict__ rowinv, float* __restrict__ out)
{
    const int na = min(nw_p[0], cap);
    const int tid = threadIdx.x;
    for (int it = blockIdx.x; it < na * NCH; it += gridDim.x) {
        const int r = it >> 4, c = it & (NCH - 1);
        const float m = rowm[r], inv = rowinv[r];
        const size_t b = (size_t)r * LSEQ;
        const int k0 = c * CHK + tid;
        out[b + k0]       = __expf(scores[b + k0] - m) * inv;
        out[b + k0 + 256] = __expf(scores[b + k0 + 256] - m) * inv;
    }
}

// K6: fallback (exact r3 attn) for rows in [cap, nw) — never active when
// nw <= cap (nw~7 in practice); guarantees correctness for any nw.
__global__ __launch_bounds__(256) void attn_fb_k(
    const float* __restrict__ Qp, const float* __restrict__ Kp,
    const int* __restrict__ nw_p, int cap, float* __restrict__ out)
{
    const int r = blockIdx.x;
    const int nw = nw_p[0];
    if (r < cap || r >= nw) return;
    const int tid = threadIdx.x;

    __shared__ float srow[LSEQ];
    __shared__ float4 q4s[16];
    __shared__ float red[4];

    if (tid < 16) q4s[tid] = ((const float4*)(Qp + (size_t)r * D))[tid];
    __syncthreads();
    float4 qr[16];
#pragma unroll
    for (int k = 0; k < 16; ++k) qr[k] = q4s[k];

    for (int l = tid; l < LSEQ; l += 256) {
        const float4* k4 = (const float4*)(Kp + (size_t)l * D);
        float s = 0.f;
#pragma unroll
        for (int k = 0; k < 16; ++k) {
            float4 kv = k4[k];
            s = fmaf(kv.x, qr[k].x, fmaf(kv.y, qr[k].y, fmaf(kv.z, qr[k].z, fmaf(kv.w, qr[k].w, s))));
        }
        srow[l] = s * PSCALE;
    }
    __syncthreads();

    float m = -3.4e38f;
    for (int l = tid; l < LSEQ; l += 256) m = fmaxf(m, srow[l]);
#pragma unroll
    for (int off = 32; off; off >>= 1) m = fmaxf(m, __shfl_xor(m, off));
    if ((tid & 63) == 0) red[tid >> 6] = m;
    __syncthreads();
    m = fmaxf(fmaxf(red[0], red[1]), fmaxf(red[2], red[3]));
    __syncthreads();

    float s = 0.f;
    for (int l = tid; l < LSEQ; l += 256) { float e = __expf(srow[l] - m); srow[l] = e; s += e; }
#pragma unroll
    for (int off = 32; off; off >>= 1) s += __shfl_xor(s, off);
    if ((tid & 63) == 0) red[tid >> 6] = s;
    __syncthreads();
    s = red[0] + red[1] + red[2] + red[3];
    float inv = 1.0f / s;

    float4* o4 = (float4*)(out + (size_t)r * LSEQ);
    const float4* s4 = (const float4*)srow;
    for (int i = tid; i < LSEQ / 4; i += 256) {
        float4 v = s4[i];
        v.x *= inv; v.y *= inv; v.z *= inv; v.w *= inv;
        o4[i] = v;
    }
}

// K7: rows >= nw are identical -> replicate row nw-1 (exact r3 form, P~30us).
__global__ __launch_bounds__(256) void repl_k(
    float* __restrict__ out, const int* __restrict__ nw_p)
{
    int r = blockIdx.x;
    int nw = nw_p[0];
    if (r < nw) return;
    const float4* src = (const float4*)(out + (size_t)(nw - 1) * LSEQ);
    float4* dst = (float4*)(out + (size_t)r * LSEQ);
    for (int i = threadIdx.x; i < LSEQ / 4; i += 256) dst[i] = src[i];
}

extern "C" void kernel_launch(void* const* d_in, const int* in_sizes, int n_in,
                              void* d_out, int out_size, void* d_ws, size_t ws_size,
                              hipStream_t stream)
{
    const float* enc  = (const float*)d_in[1];
    const float* W_ih = (const float*)d_in[2];
    // d_in[3] = W_hh multiplies the always-zero LSTM hidden state -> unused.
    const float* b_ih = (const float*)d_in[4];
    const float* b_hh = (const float*)d_in[5];
    const float* Wq   = (const float*)d_in[6];
    const float* bq   = (const float*)d_in[7];
    const float* Wk   = (const float*)d_in[8];
    const float* bk   = (const float*)d_in[9];

    float* out = (float*)d_out;                       // pointers: 8192*8192
    float* hs  = out + (size_t)T_STEPS * LSEQ;        // hs: 8192*256 (2nd output)

    // ws layout (floats): nw(16) | hstar(256) | Kp(512K) | Qp(512K) |
    //   then CAP rows of {rowm(1), rowinv(1), cmax(16), csum(16), scores(8192)}
    float* wsf   = (float*)d_ws;
    int*   nw_p  = (int*)d_ws;
    float* hstar = wsf + 16;
    float* Kp    = wsf + 16 + 256;
    float* Qp    = Kp + (size_t)LSEQ * D;
    size_t off_dyn = 16 + 256 + 2 * (size_t)LSEQ * D;   // 1048848 floats

    size_t wsf_count = ws_size / 4;
    long cap_l = 0;
    if (wsf_count > off_dyn)
        cap_l = (long)((wsf_count - off_dyn) / (LSEQ + 2 * NCH + 2));
    if (cap_l > T_STEPS) cap_l = T_STEPS;
    const int CAP = (int)cap_l;

    float* rowm   = wsf + off_dyn;
    float* rowinv = rowm + CAP;
    float* cmax   = rowinv + CAP;
    float* csum   = cmax + (size_t)CAP * NCH;
    float* scores = csum + (size_t)CAP * NCH;

    rnn_kp_k<<<513, 512, 0, stream>>>(enc, W_ih, b_ih, b_hh, Wk, bk, Kp, hs, hstar, nw_p);
    prep_k<<<2048, 256, 0, stream>>>(hs, Wq, bq, Qp, hstar, hs, nw_p);
    attnA_k<<<1024, 256, 0, stream>>>(Qp, Kp, nw_p, CAP, scores, cmax, csum);
    attnB_k<<<64, 64, 0, stream>>>(nw_p, CAP, cmax, csum, rowm, rowinv);
    attnC_k<<<2048, 256, 0, stream>>>(nw_p, CAP, scores, rowm, rowinv, out);
    attn_fb_k<<<T_STEPS, 256, 0, stream>>>(Qp, Kp, nw_p, CAP, out);
    repl_k<<<T_STEPS, 256, 0, stream>>>(out, nw_p);
}

// Round 8
// 171.756 us; speedup vs baseline: 8.6212x; 1.5413x over previous
//
#include <hip/hip_runtime.h>
#include <stdint.h>

#define T_STEPS 8192
#define LSEQ    8192
#define H       256
#define D       64
#define PSCALE  0.125f   // 1/sqrt(64)
#define CONV_EPS 4e-4f   // convergence tolerance (validated: nw ~ 7)
#define NCH     16       // score chunks per row
#define CHK     512      // keys per chunk (NCH*CHK == LSEQ)

typedef _Float16 half2_t __attribute__((ext_vector_type(2)));

#if __has_builtin(__builtin_amdgcn_fdot2)
#define FDOT2(a, b, c) __builtin_amdgcn_fdot2((a), (b), (c), false)
#else
#define FDOT2(a, b, c) fmaf((float)(a).x, (float)(b).x, fmaf((float)(a).y, (float)(b).y, (c)))
#endif

// ---------------------------------------------------------------------------
// K1: block 0 = LSTM recurrence (exact r3 structure; ~17us, nw~7).
//     block 1 = transpose Wk,Wq -> WT2 layout: WT2[k0*64+d] (float4) =
//     W[d][4k0..4k0+3]. One-time 128KB shuffle so the projections read W
//     COALESCED (the r3..r7 d=lane gather was 64 cache lines per wave-inst
//     -> 54us+ floor; rocprof r7: 194us dispatch, VALUBusy 1.8%).
// ---------------------------------------------------------------------------
__global__ __launch_bounds__(512, 2) void rnn_tr_k(
    const float* __restrict__ enc, const float* __restrict__ W_ih,
    const float* __restrict__ b_ih, const float* __restrict__ b_hh,
    const float* __restrict__ Wk, const float* __restrict__ Wq,
    float* __restrict__ WTk, float* __restrict__ WTq,
    float* __restrict__ hs_out, float* __restrict__ hstar, int* __restrict__ nw_out)
{
    if (blockIdx.x == 1) {
        const int t = threadIdx.x;
#pragma unroll
        for (int i = 0; i < 8; ++i) {
            int flat = t + 512 * i;          // [0,4096): d = flat&63, k0 = flat>>6
            int d = flat & 63, k0 = flat >> 6;
            ((float4*)WTk)[flat] = *(const float4*)(Wk + d * H + k0 * 4);
            ((float4*)WTq)[flat] = *(const float4*)(Wq + d * H + k0 * 4);
        }
        return;
    }

    // ---- block 0: the recurrence, exact r3 structure ----
    const int tid = threadIdx.x;
    const int j  = tid >> 1;          // hidden element [0,256)
    const int kc = tid & 1;           // K-chunk: cols [128*kc, 128*kc+128)

    half2_t wi[64], wg[64], wo[64];
    {
        const float4* Wi = (const float4*)(W_ih + (size_t)j * H + 128 * kc);
        const float4* Wg = (const float4*)(W_ih + (size_t)(512 + j) * H + 128 * kc);
        const float4* Wo = (const float4*)(W_ih + (size_t)(768 + j) * H + 128 * kc);
#pragma unroll
        for (int p = 0; p < 32; ++p) {
            float4 a = Wi[p], b = Wg[p], c = Wo[p];
            half2_t x;
            x.x = (_Float16)a.x; x.y = (_Float16)a.y; wi[2 * p] = x;
            x.x = (_Float16)a.z; x.y = (_Float16)a.w; wi[2 * p + 1] = x;
            x.x = (_Float16)b.x; x.y = (_Float16)b.y; wg[2 * p] = x;
            x.x = (_Float16)b.z; x.y = (_Float16)b.w; wg[2 * p + 1] = x;
            x.x = (_Float16)c.x; x.y = (_Float16)c.y; wo[2 * p] = x;
            x.x = (_Float16)c.z; x.y = (_Float16)c.w; wo[2 * p + 1] = x;
        }
    }
    const float bi = b_ih[j] + b_hh[j];
    const float bg = b_ih[512 + j] + b_hh[512 + j];
    const float bo = b_ih[768 + j] + b_hh[768 + j];

    __shared__ half2_t hp[H / 2];     // h_{t-1} packed f16x2, broadcast-read

    float hcur = enc[(size_t)(LSEQ - 1) * H + j];   // h0 = enc[-1]
    {
        float hnext = __shfl_xor(hcur, 2);          // pack partner h_{j^1}
        if ((tid & 3) == 0) { half2_t p; p.x = (_Float16)hcur; p.y = (_Float16)hnext; hp[tid >> 2] = p; }
    }
    __syncthreads();

    int nw = T_STEPS;
    int streak = 0;
    for (int t = 1; t <= T_STEPS; ++t) {
        float ai = 0.f, ag = 0.f, ao = 0.f;
        const uint4* hp4 = (const uint4*)hp;        // 16 uint4 per K-chunk
#pragma unroll
        for (int q = 0; q < 16; ++q) {
            uint4 u = hp4[kc * 16 + q];
            half2_t h0 = __builtin_bit_cast(half2_t, u.x);
            half2_t h1 = __builtin_bit_cast(half2_t, u.y);
            half2_t h2 = __builtin_bit_cast(half2_t, u.z);
            half2_t h3 = __builtin_bit_cast(half2_t, u.w);
            ai = FDOT2(wi[4 * q + 0], h0, ai); ag = FDOT2(wg[4 * q + 0], h0, ag); ao = FDOT2(wo[4 * q + 0], h0, ao);
            ai = FDOT2(wi[4 * q + 1], h1, ai); ag = FDOT2(wg[4 * q + 1], h1, ag); ao = FDOT2(wo[4 * q + 1], h1, ao);
            ai = FDOT2(wi[4 * q + 2], h2, ai); ag = FDOT2(wg[4 * q + 2], h2, ag); ao = FDOT2(wo[4 * q + 2], h2, ao);
            ai = FDOT2(wi[4 * q + 3], h3, ai); ag = FDOT2(wg[4 * q + 3], h3, ag); ao = FDOT2(wo[4 * q + 3], h3, ao);
        }
        ai += __shfl_xor(ai, 1); ag += __shfl_xor(ag, 1); ao += __shfl_xor(ao, 1);
        ai += bi; ag += bg; ao += bo;

        float si = 1.0f / (1.0f + __expf(-ai));
        float eg = __expf(-2.0f * ag); float tg = (1.0f - eg) / (1.0f + eg);
        float so = 1.0f / (1.0f + __expf(-ao));
        float c  = si * tg;
        float ec = __expf(-2.0f * c);  float tc = (1.0f - ec) / (1.0f + ec);
        float hn = so * tc;

        int moving = (kc == 0 && fabsf(hn - hcur) >= CONV_EPS) ? 1 : 0;
        int nmov = __syncthreads_count(moving);     // guards hp reads

        hcur = hn;
        float hnext = __shfl_xor(hn, 2);
        if ((tid & 3) == 0) { half2_t p; p.x = (_Float16)hn; p.y = (_Float16)hnext; hp[tid >> 2] = p; }
        if (kc == 0) hs_out[(size_t)(t - 1) * H + j] = hn;
        __syncthreads();                            // publish new hp

        streak = (nmov == 0) ? streak + 1 : 0;
        if (streak >= 2) { nw = t; break; }
    }
    if (kc == 0) hstar[j] = hcur;
    if (tid == 0) nw_out[0] = nw;
}

// ---------------------------------------------------------------------------
// K2: fused projections + fill. One wave per row; lane = output dim d.
// wt4 = WT2[k0*64+lane] is a coalesced 1KB load (L1/L2-hot, 64KB matrix);
// enc4/hs4 are wave-uniform broadcast loads. Same fmaf nesting as r3 ->
// bitwise-identical Kp/Qp.
// ---------------------------------------------------------------------------
__global__ __launch_bounds__(256) void projfill_k(
    const float* __restrict__ enc, const float* __restrict__ hs_in,
    const float* __restrict__ WTk, const float* __restrict__ WTq,
    const float* __restrict__ bk, const float* __restrict__ bq,
    float* __restrict__ Kp, float* __restrict__ Qp,
    const float* __restrict__ hstar, float* __restrict__ hs_out,
    const int* __restrict__ nw_p)
{
    const int nw   = nw_p[0];
    const int lane = threadIdx.x & 63;
    const int wid  = (blockIdx.x * 256 + threadIdx.x) >> 6;
    const int nwv  = gridDim.x * 4;
    const float bkl = bk[lane], bql = bq[lane];
    const float4* wk4 = (const float4*)WTk;
    const float4* wq4 = (const float4*)WTq;

    // Kp over all LSEQ rows
    for (int r = wid; r < LSEQ; r += nwv) {
        const float4* e4 = (const float4*)(enc + (size_t)r * H);
        float s = 0.f;
#pragma unroll 8
        for (int k0 = 0; k0 < 64; ++k0) {
            float4 a = e4[k0];
            float4 w = wk4[k0 * 64 + lane];
            s = fmaf(a.x, w.x, fmaf(a.y, w.y, fmaf(a.z, w.z, fmaf(a.w, w.w, s))));
        }
        Kp[(size_t)r * D + lane] = bkl + s;
    }

    // Qp over the nw distinct rows
    for (int r = wid; r < nw; r += nwv) {
        const float4* e4 = (const float4*)(hs_in + (size_t)r * H);
        float s = 0.f;
#pragma unroll 8
        for (int k0 = 0; k0 < 64; ++k0) {
            float4 a = e4[k0];
            float4 w = wq4[k0 * 64 + lane];
            s = fmaf(a.x, w.x, fmaf(a.y, w.y, fmaf(a.z, w.z, fmaf(a.w, w.w, s))));
        }
        Qp[(size_t)r * D + lane] = bql + s;
    }

    // fill hs[nw..T) with h*
    float4 hv = ((const float4*)hstar)[lane];
    for (int r = nw + wid; r < T_STEPS; r += nwv)
        ((float4*)(hs_out + (size_t)r * H))[lane] = hv;
}

// ---------------------------------------------------------------------------
// K3: attnA — chunked QK^T. Item (r,c): 512 scores -> ws, plus chunk max and
// chunk sum of exp(s - cmax). Persistent grid; fixed-order reductions.
// ---------------------------------------------------------------------------
__global__ __launch_bounds__(256) void attnA_k(
    const float* __restrict__ Qp, const float* __restrict__ Kp,
    const int* __restrict__ nw_p, int cap,
    float* __restrict__ scores, float* __restrict__ cmax, float* __restrict__ csum)
{
    const int na = min(nw_p[0], cap);
    const int tid = threadIdx.x;
    __shared__ float4 q4s[16];
    __shared__ float red[4];

    for (int it = blockIdx.x; it < na * NCH; it += gridDim.x) {
        const int r = it >> 4, c = it & (NCH - 1);
        if (tid < 16) q4s[tid] = ((const float4*)(Qp + (size_t)r * D))[tid];
        __syncthreads();
        float4 qr[16];
#pragma unroll
        for (int k = 0; k < 16; ++k) qr[k] = q4s[k];

        const int k0 = c * CHK + tid;         // and k0+256
        float s01[2];
#pragma unroll
        for (int h = 0; h < 2; ++h) {
            const float4* k4 = (const float4*)(Kp + (size_t)(k0 + 256 * h) * D);
            float s = 0.f;
#pragma unroll
            for (int k = 0; k < 16; ++k) {
                float4 kv = k4[k];
                s = fmaf(kv.x, qr[k].x, fmaf(kv.y, qr[k].y, fmaf(kv.z, qr[k].z, fmaf(kv.w, qr[k].w, s))));
            }
            s01[h] = s * PSCALE;
            scores[(size_t)r * LSEQ + k0 + 256 * h] = s01[h];
        }

        float m = fmaxf(s01[0], s01[1]);
#pragma unroll
        for (int off = 32; off; off >>= 1) m = fmaxf(m, __shfl_xor(m, off));
        if ((tid & 63) == 0) red[tid >> 6] = m;
        __syncthreads();
        m = fmaxf(fmaxf(red[0], red[1]), fmaxf(red[2], red[3]));
        __syncthreads();                       // red reuse guard

        float e = __expf(s01[0] - m) + __expf(s01[1] - m);
#pragma unroll
        for (int off = 32; off; off >>= 1) e += __shfl_xor(e, off);
        if ((tid & 63) == 0) red[tid >> 6] = e;
        __syncthreads();
        if (tid == 0) { cmax[it] = m; csum[it] = red[0] + red[1] + red[2] + red[3]; }
        __syncthreads();                       // red/q4s guard for next item
    }
}

// K4: attnB — exact log-sum-exp combine of the 16 chunk partials per row.
__global__ __launch_bounds__(64) void attnB_k(
    const int* __restrict__ nw_p, int cap,
    const float* __restrict__ cmax, const float* __restrict__ csum,
    float* __restrict__ rowm, float* __restrict__ rowinv)
{
    const int na = min(nw_p[0], cap);
    const int lane = threadIdx.x;
    for (int r = blockIdx.x; r < na; r += gridDim.x) {
        float cm = (lane < NCH) ? cmax[r * NCH + lane] : -3.4e38f;
        float m = cm;
#pragma unroll
        for (int off = 32; off; off >>= 1) m = fmaxf(m, __shfl_xor(m, off));
        float v = (lane < NCH) ? csum[r * NCH + lane] * __expf(cm - m) : 0.f;
#pragma unroll
        for (int off = 32; off; off >>= 1) v += __shfl_xor(v, off);
        if (lane == 0) { rowm[r] = m; rowinv[r] = 1.0f / v; }
    }
}

// K5: attnC — normalize + write the 32KB output row, chunked, persistent.
__global__ __launch_bounds__(256) void attnC_k(
    const int* __restrict__ nw_p, int cap,
    const float* __restrict__ scores, const float* __restrict__ rowm,
    const float* __restrict__ rowinv, float* __restrict__ out)
{
    const int na = min(nw_p[0], cap);
    const int tid = threadIdx.x;
    for (int it = blockIdx.x; it < na * NCH; it += gridDim.x) {
        const int r = it >> 4, c = it & (NCH - 1);
        const float m = rowm[r], inv = rowinv[r];
        const size_t b = (size_t)r * LSEQ;
        const int k0 = c * CHK + tid;
        out[b + k0]       = __expf(scores[b + k0] - m) * inv;
        out[b + k0 + 256] = __expf(scores[b + k0 + 256] - m) * inv;
    }
}

// K6: fallback (exact r3 attn) for rows in [cap, nw) — never active when
// nw <= cap (nw~7 in practice); guarantees correctness for any nw.
__global__ __launch_bounds__(256) void attn_fb_k(
    const float* __restrict__ Qp, const float* __restrict__ Kp,
    const int* __restrict__ nw_p, int cap, float* __restrict__ out)
{
    const int r = blockIdx.x;
    const int nw = nw_p[0];
    if (r < cap || r >= nw) return;
    const int tid = threadIdx.x;

    __shared__ float srow[LSEQ];
    __shared__ float4 q4s[16];
    __shared__ float red[4];

    if (tid < 16) q4s[tid] = ((const float4*)(Qp + (size_t)r * D))[tid];
    __syncthreads();
    float4 qr[16];
#pragma unroll
    for (int k = 0; k < 16; ++k) qr[k] = q4s[k];

    for (int l = tid; l < LSEQ; l += 256) {
        const float4* k4 = (const float4*)(Kp + (size_t)l * D);
        float s = 0.f;
#pragma unroll
        for (int k = 0; k < 16; ++k) {
            float4 kv = k4[k];
            s = fmaf(kv.x, qr[k].x, fmaf(kv.y, qr[k].y, fmaf(kv.z, qr[k].z, fmaf(kv.w, qr[k].w, s))));
        }
        srow[l] = s * PSCALE;
    }
    __syncthreads();

    float m = -3.4e38f;
    for (int l = tid; l < LSEQ; l += 256) m = fmaxf(m, srow[l]);
#pragma unroll
    for (int off = 32; off; off >>= 1) m = fmaxf(m, __shfl_xor(m, off));
    if ((tid & 63) == 0) red[tid >> 6] = m;
    __syncthreads();
    m = fmaxf(fmaxf(red[0], red[1]), fmaxf(red[2], red[3]));
    __syncthreads();

    float s = 0.f;
    for (int l = tid; l < LSEQ; l += 256) { float e = __expf(srow[l] - m); srow[l] = e; s += e; }
#pragma unroll
    for (int off = 32; off; off >>= 1) s += __shfl_xor(s, off);
    if ((tid & 63) == 0) red[tid >> 6] = s;
    __syncthreads();
    s = red[0] + red[1] + red[2] + red[3];
    float inv = 1.0f / s;

    float4* o4 = (float4*)(out + (size_t)r * LSEQ);
    const float4* s4 = (const float4*)srow;
    for (int i = tid; i < LSEQ / 4; i += 256) {
        float4 v = s4[i];
        v.x *= inv; v.y *= inv; v.z *= inv; v.w *= inv;
        o4[i] = v;
    }
}

// K7: rows >= nw are identical -> replicate row nw-1 (exact r3 form; ~40us =
// 268MB write at ~7TB/s, the structural floor of this problem).
__global__ __launch_bounds__(256) void repl_k(
    float* __restrict__ out, const int* __restrict__ nw_p)
{
    int r = blockIdx.x;
    int nw = nw_p[0];
    if (r < nw) return;
    const float4* src = (const float4*)(out + (size_t)(nw - 1) * LSEQ);
    float4* dst = (float4*)(out + (size_t)r * LSEQ);
    for (int i = threadIdx.x; i < LSEQ / 4; i += 256) dst[i] = src[i];
}

extern "C" void kernel_launch(void* const* d_in, const int* in_sizes, int n_in,
                              void* d_out, int out_size, void* d_ws, size_t ws_size,
                              hipStream_t stream)
{
    const float* enc  = (const float*)d_in[1];
    const float* W_ih = (const float*)d_in[2];
    // d_in[3] = W_hh multiplies the always-zero LSTM hidden state -> unused.
    const float* b_ih = (const float*)d_in[4];
    const float* b_hh = (const float*)d_in[5];
    const float* Wq   = (const float*)d_in[6];
    const float* bq   = (const float*)d_in[7];
    const float* Wk   = (const float*)d_in[8];
    const float* bk   = (const float*)d_in[9];

    float* out = (float*)d_out;                       // pointers: 8192*8192
    float* hs  = out + (size_t)T_STEPS * LSEQ;        // hs: 8192*256 (2nd output)

    // ws layout (floats): nw(16) | hstar(256) | Kp(512K) | Qp(512K) |
    //   WTk(16K) | WTq(16K) | then CAP rows of {rowm, rowinv, cmax(16),
    //   csum(16), scores(8192)}
    float* wsf   = (float*)d_ws;
    int*   nw_p  = (int*)d_ws;
    float* hstar = wsf + 16;
    float* Kp    = wsf + 16 + 256;
    float* Qp    = Kp + (size_t)LSEQ * D;
    float* WTk   = Qp + (size_t)LSEQ * D;
    float* WTq   = WTk + 64 * H;
    size_t off_dyn = 16 + 256 + 2 * (size_t)LSEQ * D + 2 * (size_t)64 * H;

    size_t wsf_count = ws_size / 4;
    long cap_l = 0;
    if (wsf_count > off_dyn)
        cap_l = (long)((wsf_count - off_dyn) / (LSEQ + 2 * NCH + 2));
    if (cap_l > T_STEPS) cap_l = T_STEPS;
    const int CAP = (int)cap_l;

    float* rowm   = wsf + off_dyn;
    float* rowinv = rowm + CAP;
    float* cmax   = rowinv + CAP;
    float* csum   = cmax + (size_t)CAP * NCH;
    float* scores = csum + (size_t)CAP * NCH;

    rnn_tr_k<<<2, 512, 0, stream>>>(enc, W_ih, b_ih, b_hh, Wk, Wq, WTk, WTq, hs, hstar, nw_p);
    projfill_k<<<512, 256, 0, stream>>>(enc, hs, WTk, WTq, bk, bq, Kp, Qp, hstar, hs, nw_p);
    attnA_k<<<1024, 256, 0, stream>>>(Qp, Kp, nw_p, CAP, scores, cmax, csum);
    attnB_k<<<64, 64, 0, stream>>>(nw_p, CAP, cmax, csum, rowm, rowinv);
    attnC_k<<<2048, 256, 0, stream>>>(nw_p, CAP, scores, rowm, rowinv, out);
    attn_fb_k<<<T_STEPS, 256, 0, stream>>>(Qp, Kp, nw_p, CAP, out);
    repl_k<<<T_STEPS, 256, 0, stream>>>(out, nw_p);
}

// Round 9
// 155.723 us; speedup vs baseline: 9.5089x; 1.1030x over previous
//
#include <hip/hip_runtime.h>
#include <stdint.h>

#define T_STEPS 8192
#define LSEQ    8192
#define H       256
#define D       64
#define PSCALE  0.125f   // 1/sqrt(64)
#define CONV_EPS 4e-4f   // convergence tolerance (validated: nw ~ 7)
#define NCH     16       // score chunks per row
#define CHK     512      // keys per chunk (NCH*CHK == LSEQ)

typedef _Float16 half2_t __attribute__((ext_vector_type(2)));

#if __has_builtin(__builtin_amdgcn_fdot2)
#define FDOT2(a, b, c) __builtin_amdgcn_fdot2((a), (b), (c), false)
#else
#define FDOT2(a, b, c) fmaf((float)(a).x, (float)(b).x, fmaf((float)(a).y, (float)(b).y, (c)))
#endif

// ---------------------------------------------------------------------------
// K1: block 0 = LSTM recurrence (r3 structure, nw~7).
//     block 1 = transpose Wk,Wq -> WT[k0*64+d] float4 layout so the
//     projections read W coalesced (fixed r7's 194us gather).
// ---------------------------------------------------------------------------
__global__ __launch_bounds__(512, 2) void rnn_tr_k(
    const float* __restrict__ enc, const float* __restrict__ W_ih,
    const float* __restrict__ b_ih, const float* __restrict__ b_hh,
    const float* __restrict__ Wk, const float* __restrict__ Wq,
    float* __restrict__ WTk, float* __restrict__ WTq,
    float* __restrict__ hs_out, float* __restrict__ hstar, int* __restrict__ nw_out)
{
    if (blockIdx.x == 1) {
        const int t = threadIdx.x;
#pragma unroll
        for (int i = 0; i < 8; ++i) {
            int flat = t + 512 * i;          // [0,4096): d = flat&63, k0 = flat>>6
            int d = flat & 63, k0 = flat >> 6;
            ((float4*)WTk)[flat] = *(const float4*)(Wk + d * H + k0 * 4);
            ((float4*)WTq)[flat] = *(const float4*)(Wq + d * H + k0 * 4);
        }
        return;
    }

    // ---- block 0: the recurrence, exact r3 structure ----
    const int tid = threadIdx.x;
    const int j  = tid >> 1;          // hidden element [0,256)
    const int kc = tid & 1;           // K-chunk: cols [128*kc, 128*kc+128)

    half2_t wi[64], wg[64], wo[64];
    {
        const float4* Wi = (const float4*)(W_ih + (size_t)j * H + 128 * kc);
        const float4* Wg = (const float4*)(W_ih + (size_t)(512 + j) * H + 128 * kc);
        const float4* Wo = (const float4*)(W_ih + (size_t)(768 + j) * H + 128 * kc);
#pragma unroll
        for (int p = 0; p < 32; ++p) {
            float4 a = Wi[p], b = Wg[p], c = Wo[p];
            half2_t x;
            x.x = (_Float16)a.x; x.y = (_Float16)a.y; wi[2 * p] = x;
            x.x = (_Float16)a.z; x.y = (_Float16)a.w; wi[2 * p + 1] = x;
            x.x = (_Float16)b.x; x.y = (_Float16)b.y; wg[2 * p] = x;
            x.x = (_Float16)b.z; x.y = (_Float16)b.w; wg[2 * p + 1] = x;
            x.x = (_Float16)c.x; x.y = (_Float16)c.y; wo[2 * p] = x;
            x.x = (_Float16)c.z; x.y = (_Float16)c.w; wo[2 * p + 1] = x;
        }
    }
    const float bi = b_ih[j] + b_hh[j];
    const float bg = b_ih[512 + j] + b_hh[512 + j];
    const float bo = b_ih[768 + j] + b_hh[768 + j];

    __shared__ half2_t hp[H / 2];     // h_{t-1} packed f16x2, broadcast-read

    float hcur = enc[(size_t)(LSEQ - 1) * H + j];   // h0 = enc[-1]
    {
        float hnext = __shfl_xor(hcur, 2);          // pack partner h_{j^1}
        if ((tid & 3) == 0) { half2_t p; p.x = (_Float16)hcur; p.y = (_Float16)hnext; hp[tid >> 2] = p; }
    }
    __syncthreads();

    int nw = T_STEPS;
    int streak = 0;
    for (int t = 1; t <= T_STEPS; ++t) {
        float ai = 0.f, ag = 0.f, ao = 0.f;
        const uint4* hp4 = (const uint4*)hp;        // 16 uint4 per K-chunk
#pragma unroll
        for (int q = 0; q < 16; ++q) {
            uint4 u = hp4[kc * 16 + q];
            half2_t h0 = __builtin_bit_cast(half2_t, u.x);
            half2_t h1 = __builtin_bit_cast(half2_t, u.y);
            half2_t h2 = __builtin_bit_cast(half2_t, u.z);
            half2_t h3 = __builtin_bit_cast(half2_t, u.w);
            ai = FDOT2(wi[4 * q + 0], h0, ai); ag = FDOT2(wg[4 * q + 0], h0, ag); ao = FDOT2(wo[4 * q + 0], h0, ao);
            ai = FDOT2(wi[4 * q + 1], h1, ai); ag = FDOT2(wg[4 * q + 1], h1, ag); ao = FDOT2(wo[4 * q + 1], h1, ao);
            ai = FDOT2(wi[4 * q + 2], h2, ai); ag = FDOT2(wg[4 * q + 2], h2, ag); ao = FDOT2(wo[4 * q + 2], h2, ao);
            ai = FDOT2(wi[4 * q + 3], h3, ai); ag = FDOT2(wg[4 * q + 3], h3, ag); ao = FDOT2(wo[4 * q + 3], h3, ao);
        }
        ai += __shfl_xor(ai, 1); ag += __shfl_xor(ag, 1); ao += __shfl_xor(ao, 1);
        ai += bi; ag += bg; ao += bo;

        float si = 1.0f / (1.0f + __expf(-ai));
        float eg = __expf(-2.0f * ag); float tg = (1.0f - eg) / (1.0f + eg);
        float so = 1.0f / (1.0f + __expf(-ao));
        float c  = si * tg;
        float ec = __expf(-2.0f * c);  float tc = (1.0f - ec) / (1.0f + ec);
        float hn = so * tc;

        int moving = (kc == 0 && fabsf(hn - hcur) >= CONV_EPS) ? 1 : 0;
        int nmov = __syncthreads_count(moving);     // guards hp reads

        hcur = hn;
        float hnext = __shfl_xor(hn, 2);
        if ((tid & 3) == 0) { half2_t p; p.x = (_Float16)hn; p.y = (_Float16)hnext; hp[tid >> 2] = p; }
        if (kc == 0) hs_out[(size_t)(t - 1) * H + j] = hn;
        __syncthreads();                            // publish new hp

        streak = (nmov == 0) ? streak + 1 : 0;
        if (streak >= 2) { nw = t; break; }
    }
    if (kc == 0) hstar[j] = hcur;
    if (tid == 0) nw_out[0] = nw;
}

// ---------------------------------------------------------------------------
// K2: fused projections + fill. One wave per 4 rows (Kp): the coalesced WT
// read (1KB/inst) is amortized over 4 rows -> WT L2 traffic 512->128 MB.
// Same fmaf nesting per k0 as r8 -> bitwise-identical Kp/Qp.
// ---------------------------------------------------------------------------
__global__ __launch_bounds__(256) void projfill_k(
    const float* __restrict__ enc, const float* __restrict__ hs_in,
    const float* __restrict__ WTk, const float* __restrict__ WTq,
    const float* __restrict__ bk, const float* __restrict__ bq,
    float* __restrict__ Kp, float* __restrict__ Qp,
    const float* __restrict__ hstar, float* __restrict__ hs_out,
    const int* __restrict__ nw_p)
{
    const int nw   = nw_p[0];
    const int lane = threadIdx.x & 63;
    const int wid  = (blockIdx.x * 256 + threadIdx.x) >> 6;   // 0..2047
    const int nwv  = gridDim.x * 4;
    const float bkl = bk[lane], bql = bq[lane];
    const float4* wk4 = (const float4*)WTk;
    const float4* wq4 = (const float4*)WTq;

    // Kp over all LSEQ rows, 4 rows per wave
    for (int r0 = wid * 4; r0 < LSEQ; r0 += nwv * 4) {
        const float4* e0 = (const float4*)(enc + (size_t)(r0 + 0) * H);
        const float4* e1 = (const float4*)(enc + (size_t)(r0 + 1) * H);
        const float4* e2 = (const float4*)(enc + (size_t)(r0 + 2) * H);
        const float4* e3 = (const float4*)(enc + (size_t)(r0 + 3) * H);
        float s0 = 0.f, s1 = 0.f, s2 = 0.f, s3 = 0.f;
#pragma unroll 8
        for (int k0 = 0; k0 < 64; ++k0) {
            float4 w = wk4[k0 * 64 + lane];
            float4 a0 = e0[k0], a1 = e1[k0], a2 = e2[k0], a3 = e3[k0];
            s0 = fmaf(a0.x, w.x, fmaf(a0.y, w.y, fmaf(a0.z, w.z, fmaf(a0.w, w.w, s0))));
            s1 = fmaf(a1.x, w.x, fmaf(a1.y, w.y, fmaf(a1.z, w.z, fmaf(a1.w, w.w, s1))));
            s2 = fmaf(a2.x, w.x, fmaf(a2.y, w.y, fmaf(a2.z, w.z, fmaf(a2.w, w.w, s2))));
            s3 = fmaf(a3.x, w.x, fmaf(a3.y, w.y, fmaf(a3.z, w.z, fmaf(a3.w, w.w, s3))));
        }
        Kp[(size_t)(r0 + 0) * D + lane] = bkl + s0;
        Kp[(size_t)(r0 + 1) * D + lane] = bkl + s1;
        Kp[(size_t)(r0 + 2) * D + lane] = bkl + s2;
        Kp[(size_t)(r0 + 3) * D + lane] = bkl + s3;
    }

    // Qp over the nw distinct rows (tiny)
    for (int r = wid; r < nw; r += nwv) {
        const float4* e4 = (const float4*)(hs_in + (size_t)r * H);
        float s = 0.f;
#pragma unroll 8
        for (int k0 = 0; k0 < 64; ++k0) {
            float4 a = e4[k0];
            float4 w = wq4[k0 * 64 + lane];
            s = fmaf(a.x, w.x, fmaf(a.y, w.y, fmaf(a.z, w.z, fmaf(a.w, w.w, s))));
        }
        Qp[(size_t)r * D + lane] = bql + s;
    }

    // fill hs[nw..T) with h*
    float4 hv = ((const float4*)hstar)[lane];
    for (int r = nw + wid; r < T_STEPS; r += nwv)
        ((float4*)(hs_out + (size_t)r * H))[lane] = hv;
}

// ---------------------------------------------------------------------------
// K3: attnA — chunked QK^T. Item (r,c): 512 scores -> ws, plus chunk max and
// chunk sum of exp(s - cmax). Persistent grid; fixed-order reductions.
// ---------------------------------------------------------------------------
__global__ __launch_bounds__(256) void attnA_k(
    const float* __restrict__ Qp, const float* __restrict__ Kp,
    const int* __restrict__ nw_p, int cap,
    float* __restrict__ scores, float* __restrict__ cmax, float* __restrict__ csum)
{
    const int na = min(nw_p[0], cap);
    const int tid = threadIdx.x;
    __shared__ float4 q4s[16];
    __shared__ float red[4];

    for (int it = blockIdx.x; it < na * NCH; it += gridDim.x) {
        const int r = it >> 4, c = it & (NCH - 1);
        if (tid < 16) q4s[tid] = ((const float4*)(Qp + (size_t)r * D))[tid];
        __syncthreads();
        float4 qr[16];
#pragma unroll
        for (int k = 0; k < 16; ++k) qr[k] = q4s[k];

        const int k0 = c * CHK + tid;         // and k0+256
        float s01[2];
#pragma unroll
        for (int h = 0; h < 2; ++h) {
            const float4* k4 = (const float4*)(Kp + (size_t)(k0 + 256 * h) * D);
            float s = 0.f;
#pragma unroll
            for (int k = 0; k < 16; ++k) {
                float4 kv = k4[k];
                s = fmaf(kv.x, qr[k].x, fmaf(kv.y, qr[k].y, fmaf(kv.z, qr[k].z, fmaf(kv.w, qr[k].w, s))));
            }
            s01[h] = s * PSCALE;
            scores[(size_t)r * LSEQ + k0 + 256 * h] = s01[h];
        }

        float m = fmaxf(s01[0], s01[1]);
#pragma unroll
        for (int off = 32; off; off >>= 1) m = fmaxf(m, __shfl_xor(m, off));
        if ((tid & 63) == 0) red[tid >> 6] = m;
        __syncthreads();
        m = fmaxf(fmaxf(red[0], red[1]), fmaxf(red[2], red[3]));
        __syncthreads();                       // red reuse guard

        float e = __expf(s01[0] - m) + __expf(s01[1] - m);
#pragma unroll
        for (int off = 32; off; off >>= 1) e += __shfl_xor(e, off);
        if ((tid & 63) == 0) red[tid >> 6] = e;
        __syncthreads();
        if (tid == 0) { cmax[it] = m; csum[it] = red[0] + red[1] + red[2] + red[3]; }
        __syncthreads();                       // red/q4s guard for next item
    }
}

// ---------------------------------------------------------------------------
// K4: attnCall — merged LSE-combine + normalize + duplicate-row replicate.
// Grid-strides over ALL 8192 output rows; source row rs = min(r, nw-1).
// The duplicated source row (32KB) is L1-resident per CU -> pure write BW
// (~268MB, the structural floor). exp-recompute of duplicates is bitwise
// identical across rows (same inputs, same ops).
// ---------------------------------------------------------------------------
__global__ __launch_bounds__(256) void attnCall_k(
    const int* __restrict__ nw_p, int cap,
    const float* __restrict__ scores, const float* __restrict__ cmax,
    const float* __restrict__ csum, float* __restrict__ out)
{
    const int nw = nw_p[0];
    const int na = min(nw, cap);
    const int tid = threadIdx.x;

    for (int r = blockIdx.x; r < T_STEPS; r += gridDim.x) {
        const int rs = min(r, nw - 1);
        if (rs >= na) continue;                // only possible when nw > cap -> fb
        // per-thread LSE combine of the 16 chunk partials (broadcast loads)
        float m = -3.4e38f;
#pragma unroll
        for (int c = 0; c < NCH; ++c) m = fmaxf(m, cmax[rs * NCH + c]);
        float v = 0.f;
#pragma unroll
        for (int c = 0; c < NCH; ++c) v += csum[rs * NCH + c] * __expf(cmax[rs * NCH + c] - m);
        const float inv = 1.0f / v;

        const float4* s4 = (const float4*)(scores + (size_t)rs * LSEQ);
        float4* o4 = (float4*)(out + (size_t)r * LSEQ);
        for (int i = tid; i < LSEQ / 4; i += 256) {
            float4 sv = s4[i];
            float4 ov;
            ov.x = __expf(sv.x - m) * inv;
            ov.y = __expf(sv.y - m) * inv;
            ov.z = __expf(sv.z - m) * inv;
            ov.w = __expf(sv.w - m) * inv;
            o4[i] = ov;
        }
    }
}

// ---------------------------------------------------------------------------
// K5: fallback for source rows >= cap (only launched when CAP < T_STEPS;
// with the provided ws it never is). Full softmax of row rs -> out row r.
// ---------------------------------------------------------------------------
__global__ __launch_bounds__(256) void attn_fb_k(
    const float* __restrict__ Qp, const float* __restrict__ Kp,
    const int* __restrict__ nw_p, int cap, float* __restrict__ out)
{
    const int r = blockIdx.x;
    const int nw = nw_p[0];
    const int rs = min(r, nw - 1);
    if (rs < cap) return;
    const int tid = threadIdx.x;

    __shared__ float srow[LSEQ];
    __shared__ float4 q4s[16];
    __shared__ float red[4];

    if (tid < 16) q4s[tid] = ((const float4*)(Qp + (size_t)rs * D))[tid];
    __syncthreads();
    float4 qr[16];
#pragma unroll
    for (int k = 0; k < 16; ++k) qr[k] = q4s[k];

    for (int l = tid; l < LSEQ; l += 256) {
        const float4* k4 = (const float4*)(Kp + (size_t)l * D);
        float s = 0.f;
#pragma unroll
        for (int k = 0; k < 16; ++k) {
            float4 kv = k4[k];
            s = fmaf(kv.x, qr[k].x, fmaf(kv.y, qr[k].y, fmaf(kv.z, qr[k].z, fmaf(kv.w, qr[k].w, s))));
        }
        srow[l] = s * PSCALE;
    }
    __syncthreads();

    float m = -3.4e38f;
    for (int l = tid; l < LSEQ; l += 256) m = fmaxf(m, srow[l]);
#pragma unroll
    for (int off = 32; off; off >>= 1) m = fmaxf(m, __shfl_xor(m, off));
    if ((tid & 63) == 0) red[tid >> 6] = m;
    __syncthreads();
    m = fmaxf(fmaxf(red[0], red[1]), fmaxf(red[2], red[3]));
    __syncthreads();

    float s = 0.f;
    for (int l = tid; l < LSEQ; l += 256) { float e = __expf(srow[l] - m); srow[l] = e; s += e; }
#pragma unroll
    for (int off = 32; off; off >>= 1) s += __shfl_xor(s, off);
    if ((tid & 63) == 0) red[tid >> 6] = s;
    __syncthreads();
    s = red[0] + red[1] + red[2] + red[3];
    float inv = 1.0f / s;

    float4* o4 = (float4*)(out + (size_t)r * LSEQ);
    const float4* s4 = (const float4*)srow;
    for (int i = tid; i < LSEQ / 4; i += 256) {
        float4 v = s4[i];
        v.x *= inv; v.y *= inv; v.z *= inv; v.w *= inv;
        o4[i] = v;
    }
}

extern "C" void kernel_launch(void* const* d_in, const int* in_sizes, int n_in,
                              void* d_out, int out_size, void* d_ws, size_t ws_size,
                              hipStream_t stream)
{
    const float* enc  = (const float*)d_in[1];
    const float* W_ih = (const float*)d_in[2];
    // d_in[3] = W_hh multiplies the always-zero LSTM hidden state -> unused.
    const float* b_ih = (const float*)d_in[4];
    const float* b_hh = (const float*)d_in[5];
    const float* Wq   = (const float*)d_in[6];
    const float* bq   = (const float*)d_in[7];
    const float* Wk   = (const float*)d_in[8];
    const float* bk   = (const float*)d_in[9];

    float* out = (float*)d_out;                       // pointers: 8192*8192
    float* hs  = out + (size_t)T_STEPS * LSEQ;        // hs: 8192*256 (2nd output)

    // ws layout (floats): nw(16) | hstar(256) | Kp(512K) | Qp(512K) |
    //   WTk(16K) | WTq(16K) | cmax(CAP*16) | csum(CAP*16) | scores(CAP*8192)
    float* wsf   = (float*)d_ws;
    int*   nw_p  = (int*)d_ws;
    float* hstar = wsf + 16;
    float* Kp    = wsf + 16 + 256;
    float* Qp    = Kp + (size_t)LSEQ * D;
    float* WTk   = Qp + (size_t)LSEQ * D;
    float* WTq   = WTk + 64 * H;
    size_t off_dyn = 16 + 256 + 2 * (size_t)LSEQ * D + 2 * (size_t)64 * H;

    size_t wsf_count = ws_size / 4;
    long cap_l = 0;
    if (wsf_count > off_dyn)
        cap_l = (long)((wsf_count - off_dyn) / (LSEQ + 2 * NCH));
    if (cap_l > T_STEPS) cap_l = T_STEPS;
    const int CAP = (int)cap_l;

    float* cmax   = wsf + off_dyn;
    float* csum   = cmax + (size_t)CAP * NCH;
    float* scores = csum + (size_t)CAP * NCH;

    rnn_tr_k<<<2, 512, 0, stream>>>(enc, W_ih, b_ih, b_hh, Wk, Wq, WTk, WTq, hs, hstar, nw_p);
    projfill_k<<<512, 256, 0, stream>>>(enc, hs, WTk, WTq, bk, bq, Kp, Qp, hstar, hs, nw_p);
    attnA_k<<<1024, 256, 0, stream>>>(Qp, Kp, nw_p, CAP, scores, cmax, csum);
    attnCall_k<<<2048, 256, 0, stream>>>(nw_p, CAP, scores, cmax, csum, out);
    if (CAP < T_STEPS)   // fallback only needed if scores can't hold all rows
        attn_fb_k<<<T_STEPS, 256, 0, stream>>>(Qp, Kp, nw_p, CAP, out);
}

// Round 10
// 103.988 us; speedup vs baseline: 14.2396x; 1.4975x over previous
//
#include <hip/hip_runtime.h>
#include <stdint.h>

#define T_STEPS 8192
#define LSEQ    8192
#define H       256
#define D       64
#define PSCALE  0.125f   // 1/sqrt(64)
#define CONV_EPS 4e-4f   // convergence tolerance (validated: nw ~ 7)
#define NCH     16       // score chunks per row
#define CHK     512      // keys per chunk (NCH*CHK == LSEQ)

typedef _Float16 half2_t __attribute__((ext_vector_type(2)));

#if __has_builtin(__builtin_amdgcn_fdot2)
#define FDOT2(a, b, c) __builtin_amdgcn_fdot2((a), (b), (c), false)
#else
#define FDOT2(a, b, c) fmaf((float)(a).x, (float)(b).x, fmaf((float)(a).y, (float)(b).y, (c)))
#endif

static __device__ __forceinline__ unsigned pack_f16(float a, float b) {
    half2_t h; h.x = (_Float16)a; h.y = (_Float16)b;
    return __builtin_bit_cast(unsigned, h);
}

// ---------------------------------------------------------------------------
// K0: prep — chip-wide weight staging so the single-CU rnn block doesn't pull
// 768 KB of f32 from HBM by itself (~30us at one CU's ~25 GB/s HBM share).
//  (a) W_ih (gates i,g,o) -> f16 SoA: uint4 W16v[p*512 + slot], p=0..47
//      (p = gate*16 + s), slot = j*2+kc. rnn reads 48 coalesced uint4/thread,
//      384 KB total, L2/L3-hot from this producer. Same f32->f16 rounding as
//      the old in-thread convert -> bitwise-identical weights.
//  (b) WTk/WTq transposes for the coalesced projection pattern (r8 fix).
// ---------------------------------------------------------------------------
__global__ __launch_bounds__(256) void prep_k(
    const float* __restrict__ W_ih, const float* __restrict__ Wk,
    const float* __restrict__ Wq, uint4* __restrict__ W16v,
    float* __restrict__ WTk, float* __restrict__ WTq)
{
    int flat = blockIdx.x * 256 + threadIdx.x;
    if (flat < 24576) {                 // W16v: 48*512 uint4
        int p = flat >> 9, slot = flat & 511;
        int g = p >> 4, s = p & 15;
        int j = slot >> 1, kc = slot & 1;
        const int goff = (g == 0) ? 0 : (g == 1 ? 512 : 768);
        const float* src = W_ih + (size_t)(goff + j) * H + kc * 128 + s * 8;
        uint4 u;
        u.x = pack_f16(src[0], src[1]);
        u.y = pack_f16(src[2], src[3]);
        u.z = pack_f16(src[4], src[5]);
        u.w = pack_f16(src[6], src[7]);
        W16v[flat] = u;
    } else if (flat < 24576 + 4096) {   // WT transposes: 4096 float4 each
        int f = flat - 24576;
        int d = f & 63, k0 = f >> 6;
        ((float4*)WTk)[f] = *(const float4*)(Wk + d * H + k0 * 4);
        ((float4*)WTq)[f] = *(const float4*)(Wq + d * H + k0 * 4);
    }
}

// ---------------------------------------------------------------------------
// K1: block 0 = LSTM recurrence (r3 dot structure, f16-SoA weight load);
//     blocks 1..256 = Kp projection (independent of the recurrence) riding
//     the same dispatch -> its ~6us hides under the rnn.
// ---------------------------------------------------------------------------
__global__ __launch_bounds__(512, 2) void rnn_kp_k(
    const float* __restrict__ enc, const uint4* __restrict__ W16v,
    const float* __restrict__ b_ih, const float* __restrict__ b_hh,
    const float* __restrict__ WTk, const float* __restrict__ bk,
    float* __restrict__ Kp,
    float* __restrict__ hs_out, float* __restrict__ hstar, int* __restrict__ nw_out)
{
    const int tid = threadIdx.x;
    if (blockIdx.x != 0) {
        // ---- Kp: 4 rows per wave, coalesced WTk reads (r9 pattern) ----
        const int lane = tid & 63;
        const int wid  = ((int)blockIdx.x - 1) * 8 + (tid >> 6);  // 0..2047
        const float bkl = bk[lane];
        const float4* wk4 = (const float4*)WTk;
        const int r0 = wid * 4;
        const float4* e0 = (const float4*)(enc + (size_t)(r0 + 0) * H);
        const float4* e1 = (const float4*)(enc + (size_t)(r0 + 1) * H);
        const float4* e2 = (const float4*)(enc + (size_t)(r0 + 2) * H);
        const float4* e3 = (const float4*)(enc + (size_t)(r0 + 3) * H);
        float s0 = 0.f, s1 = 0.f, s2 = 0.f, s3 = 0.f;
#pragma unroll 8
        for (int k0 = 0; k0 < 64; ++k0) {
            float4 w = wk4[k0 * 64 + lane];
            float4 a0 = e0[k0], a1 = e1[k0], a2 = e2[k0], a3 = e3[k0];
            s0 = fmaf(a0.x, w.x, fmaf(a0.y, w.y, fmaf(a0.z, w.z, fmaf(a0.w, w.w, s0))));
            s1 = fmaf(a1.x, w.x, fmaf(a1.y, w.y, fmaf(a1.z, w.z, fmaf(a1.w, w.w, s1))));
            s2 = fmaf(a2.x, w.x, fmaf(a2.y, w.y, fmaf(a2.z, w.z, fmaf(a2.w, w.w, s2))));
            s3 = fmaf(a3.x, w.x, fmaf(a3.y, w.y, fmaf(a3.z, w.z, fmaf(a3.w, w.w, s3))));
        }
        Kp[(size_t)(r0 + 0) * D + lane] = bkl + s0;
        Kp[(size_t)(r0 + 1) * D + lane] = bkl + s1;
        Kp[(size_t)(r0 + 2) * D + lane] = bkl + s2;
        Kp[(size_t)(r0 + 3) * D + lane] = bkl + s3;
        return;
    }

    // ---- block 0: the recurrence ----
    const int j  = tid >> 1;          // hidden element [0,256)
    const int kc = tid & 1;           // K-chunk: cols [128*kc, 128*kc+128)

    uint4 wv[48];                     // 48 coalesced uint4 = this thread's
#pragma unroll                        // 3x128 f16 weights (SoA from prep_k)
    for (int p = 0; p < 48; ++p) wv[p] = W16v[p * 512 + tid];

    const float bi = b_ih[j] + b_hh[j];
    const float bg = b_ih[512 + j] + b_hh[512 + j];
    const float bo = b_ih[768 + j] + b_hh[768 + j];

    __shared__ half2_t hp[H / 2];     // h_{t-1} packed f16x2, broadcast-read

    float hcur = enc[(size_t)(LSEQ - 1) * H + j];   // h0 = enc[-1]
    {
        float hnext = __shfl_xor(hcur, 2);          // pack partner h_{j^1}
        if ((tid & 3) == 0) { half2_t p; p.x = (_Float16)hcur; p.y = (_Float16)hnext; hp[tid >> 2] = p; }
    }
    __syncthreads();

    int nw = T_STEPS;
    int streak = 0;
    for (int t = 1; t <= T_STEPS; ++t) {
        float ai = 0.f, ag = 0.f, ao = 0.f;
        const uint4* hp4 = (const uint4*)hp;        // 16 uint4 per K-chunk
#pragma unroll
        for (int q = 0; q < 16; ++q) {
            uint4 u = hp4[kc * 16 + q];
            half2_t h0 = __builtin_bit_cast(half2_t, u.x);
            half2_t h1 = __builtin_bit_cast(half2_t, u.y);
            half2_t h2 = __builtin_bit_cast(half2_t, u.z);
            half2_t h3 = __builtin_bit_cast(half2_t, u.w);
            uint4 wiu = wv[q], wgu = wv[16 + q], wou = wv[32 + q];
            ai = FDOT2(__builtin_bit_cast(half2_t, wiu.x), h0, ai);
            ag = FDOT2(__builtin_bit_cast(half2_t, wgu.x), h0, ag);
            ao = FDOT2(__builtin_bit_cast(half2_t, wou.x), h0, ao);
            ai = FDOT2(__builtin_bit_cast(half2_t, wiu.y), h1, ai);
            ag = FDOT2(__builtin_bit_cast(half2_t, wgu.y), h1, ag);
            ao = FDOT2(__builtin_bit_cast(half2_t, wou.y), h1, ao);
            ai = FDOT2(__builtin_bit_cast(half2_t, wiu.z), h2, ai);
            ag = FDOT2(__builtin_bit_cast(half2_t, wgu.z), h2, ag);
            ao = FDOT2(__builtin_bit_cast(half2_t, wou.z), h2, ao);
            ai = FDOT2(__builtin_bit_cast(half2_t, wiu.w), h3, ai);
            ag = FDOT2(__builtin_bit_cast(half2_t, wgu.w), h3, ag);
            ao = FDOT2(__builtin_bit_cast(half2_t, wou.w), h3, ao);
        }
        ai += __shfl_xor(ai, 1); ag += __shfl_xor(ag, 1); ao += __shfl_xor(ao, 1);
        ai += bi; ag += bg; ao += bo;

        float si = 1.0f / (1.0f + __expf(-ai));
        float eg = __expf(-2.0f * ag); float tg = (1.0f - eg) / (1.0f + eg);
        float so = 1.0f / (1.0f + __expf(-ao));
        float c  = si * tg;
        float ec = __expf(-2.0f * c);  float tc = (1.0f - ec) / (1.0f + ec);
        float hn = so * tc;

        int moving = (kc == 0 && fabsf(hn - hcur) >= CONV_EPS) ? 1 : 0;
        int nmov = __syncthreads_count(moving);     // guards hp reads

        hcur = hn;
        float hnext = __shfl_xor(hn, 2);
        if ((tid & 3) == 0) { half2_t p; p.x = (_Float16)hn; p.y = (_Float16)hnext; hp[tid >> 2] = p; }
        if (kc == 0) hs_out[(size_t)(t - 1) * H + j] = hn;
        __syncthreads();                            // publish new hp

        streak = (nmov == 0) ? streak + 1 : 0;
        if (streak >= 2) { nw = t; break; }
    }
    if (kc == 0) hstar[j] = hcur;
    if (tid == 0) nw_out[0] = nw;
}

// ---------------------------------------------------------------------------
// K2: attnA + hs-fill. Item (r,c): compute Q[r] inline (same fmaf order as
// the old Qp projection -> identical bits), 512 scores -> ws, chunk max and
// chunk exp-sum. Then all blocks grid-stride the hs[nw..T) fill.
// ---------------------------------------------------------------------------
__global__ __launch_bounds__(256) void attnA_fill_k(
    const float* __restrict__ hs, const float* __restrict__ WTq,
    const float* __restrict__ bq, const float* __restrict__ Kp,
    const float* __restrict__ hstar, float* __restrict__ hs_out,
    const int* __restrict__ nw_p, int cap,
    float* __restrict__ scores, float* __restrict__ cmax, float* __restrict__ csum)
{
    const int nw = nw_p[0];
    const int na = min(nw, cap);
    const int tid = threadIdx.x;
    __shared__ float qrow[D];
    __shared__ float red[4];
    const float4* wq4 = (const float4*)WTq;

    for (int it = blockIdx.x; it < na * NCH; it += gridDim.x) {
        const int r = it >> 4, c = it & (NCH - 1);
        if (tid < 64) {                  // inline Q projection (bitwise == Qp)
            const float4* e4 = (const float4*)(hs + (size_t)r * H);
            float s = 0.f;
#pragma unroll 8
            for (int k0 = 0; k0 < 64; ++k0) {
                float4 a = e4[k0];
                float4 w = wq4[k0 * 64 + tid];
                s = fmaf(a.x, w.x, fmaf(a.y, w.y, fmaf(a.z, w.z, fmaf(a.w, w.w, s))));
            }
            qrow[tid] = bq[tid] + s;
        }
        __syncthreads();
        float4 qr[16];
#pragma unroll
        for (int k = 0; k < 16; ++k) qr[k] = ((const float4*)qrow)[k];

        const int k0 = c * CHK + tid;         // and k0+256
        float s01[2];
#pragma unroll
        for (int h = 0; h < 2; ++h) {
            const float4* k4 = (const float4*)(Kp + (size_t)(k0 + 256 * h) * D);
            float s = 0.f;
#pragma unroll
            for (int k = 0; k < 16; ++k) {
                float4 kv = k4[k];
                s = fmaf(kv.x, qr[k].x, fmaf(kv.y, qr[k].y, fmaf(kv.z, qr[k].z, fmaf(kv.w, qr[k].w, s))));
            }
            s01[h] = s * PSCALE;
            scores[(size_t)r * LSEQ + k0 + 256 * h] = s01[h];
        }

        float m = fmaxf(s01[0], s01[1]);
#pragma unroll
        for (int off = 32; off; off >>= 1) m = fmaxf(m, __shfl_xor(m, off));
        if ((tid & 63) == 0) red[tid >> 6] = m;
        __syncthreads();
        m = fmaxf(fmaxf(red[0], red[1]), fmaxf(red[2], red[3]));
        __syncthreads();                       // red reuse guard

        float e = __expf(s01[0] - m) + __expf(s01[1] - m);
#pragma unroll
        for (int off = 32; off; off >>= 1) e += __shfl_xor(e, off);
        if ((tid & 63) == 0) red[tid >> 6] = e;
        __syncthreads();
        if (tid == 0) { cmax[it] = m; csum[it] = red[0] + red[1] + red[2] + red[3]; }
        __syncthreads();                       // red/qrow guard for next item
    }

    // hs[nw..T) = h*  (output-only region; 4 rows per block iteration)
    float4 hv = ((const float4*)hstar)[tid & 63];
    for (int r = nw + blockIdx.x * 4 + (tid >> 6); r < T_STEPS; r += gridDim.x * 4)
        ((float4*)(hs_out + (size_t)r * H))[tid & 63] = hv;
}

// ---------------------------------------------------------------------------
// K3: attnCall — merged LSE-combine + normalize + duplicate-row replicate.
// Grid-strides ALL 8192 output rows; source row rs = min(r, nw-1). Pure
// write BW (~268 MB), the structural floor of this problem.
// ---------------------------------------------------------------------------
__global__ __launch_bounds__(256) void attnCall_k(
    const int* __restrict__ nw_p, int cap,
    const float* __restrict__ scores, const float* __restrict__ cmax,
    const float* __restrict__ csum, float* __restrict__ out)
{
    const int nw = nw_p[0];
    const int na = min(nw, cap);
    const int tid = threadIdx.x;

    for (int r = blockIdx.x; r < T_STEPS; r += gridDim.x) {
        const int rs = min(r, nw - 1);
        if (rs >= na) continue;                // only when nw > cap -> fb path
        float m = -3.4e38f;
#pragma unroll
        for (int c = 0; c < NCH; ++c) m = fmaxf(m, cmax[rs * NCH + c]);
        float v = 0.f;
#pragma unroll
        for (int c = 0; c < NCH; ++c) v += csum[rs * NCH + c] * __expf(cmax[rs * NCH + c] - m);
        const float inv = 1.0f / v;

        const float4* s4 = (const float4*)(scores + (size_t)rs * LSEQ);
        float4* o4 = (float4*)(out + (size_t)r * LSEQ);
        for (int i = tid; i < LSEQ / 4; i += 256) {
            float4 sv = s4[i];
            float4 ov;
            ov.x = __expf(sv.x - m) * inv;
            ov.y = __expf(sv.y - m) * inv;
            ov.z = __expf(sv.z - m) * inv;
            ov.w = __expf(sv.w - m) * inv;
            o4[i] = ov;
        }
    }
}

// ---------------------------------------------------------------------------
// K4: fallback for source rows >= cap (launched only when CAP < T_STEPS;
// with the provided ws it never is). Inline-Q full softmax of row rs -> r.
// ---------------------------------------------------------------------------
__global__ __launch_bounds__(256) void attn_fb_k(
    const float* __restrict__ hs, const float* __restrict__ WTq,
    const float* __restrict__ bq, const float* __restrict__ Kp,
    const int* __restrict__ nw_p, int cap, float* __restrict__ out)
{
    const int r = blockIdx.x;
    const int nw = nw_p[0];
    const int rs = min(r, nw - 1);
    if (rs < cap) return;
    const int tid = threadIdx.x;

    __shared__ float srow[LSEQ];
    __shared__ float qrow[D];
    __shared__ float red[4];
    const float4* wq4 = (const float4*)WTq;

    if (tid < 64) {
        const float4* e4 = (const float4*)(hs + (size_t)rs * H);
        float s = 0.f;
#pragma unroll 8
        for (int k0 = 0; k0 < 64; ++k0) {
            float4 a = e4[k0];
            float4 w = wq4[k0 * 64 + tid];
            s = fmaf(a.x, w.x, fmaf(a.y, w.y, fmaf(a.z, w.z, fmaf(a.w, w.w, s))));
        }
        qrow[tid] = bq[tid] + s;
    }
    __syncthreads();
    float4 qr[16];
#pragma unroll
    for (int k = 0; k < 16; ++k) qr[k] = ((const float4*)qrow)[k];

    for (int l = tid; l < LSEQ; l += 256) {
        const float4* k4 = (const float4*)(Kp + (size_t)l * D);
        float s = 0.f;
#pragma unroll
        for (int k = 0; k < 16; ++k) {
            float4 kv = k4[k];
            s = fmaf(kv.x, qr[k].x, fmaf(kv.y, qr[k].y, fmaf(kv.z, qr[k].z, fmaf(kv.w, qr[k].w, s))));
        }
        srow[l] = s * PSCALE;
    }
    __syncthreads();

    float m = -3.4e38f;
    for (int l = tid; l < LSEQ; l += 256) m = fmaxf(m, srow[l]);
#pragma unroll
    for (int off = 32; off; off >>= 1) m = fmaxf(m, __shfl_xor(m, off));
    if ((tid & 63) == 0) red[tid >> 6] = m;
    __syncthreads();
    m = fmaxf(fmaxf(red[0], red[1]), fmaxf(red[2], red[3]));
    __syncthreads();

    float s = 0.f;
    for (int l = tid; l < LSEQ; l += 256) { float e = __expf(srow[l] - m); srow[l] = e; s += e; }
#pragma unroll
    for (int off = 32; off; off >>= 1) s += __shfl_xor(s, off);
    if ((tid & 63) == 0) red[tid >> 6] = s;
    __syncthreads();
    s = red[0] + red[1] + red[2] + red[3];
    float inv = 1.0f / s;

    float4* o4 = (float4*)(out + (size_t)r * LSEQ);
    const float4* s4 = (const float4*)srow;
    for (int i = tid; i < LSEQ / 4; i += 256) {
        float4 v = s4[i];
        v.x *= inv; v.y *= inv; v.z *= inv; v.w *= inv;
        o4[i] = v;
    }
}

extern "C" void kernel_launch(void* const* d_in, const int* in_sizes, int n_in,
                              void* d_out, int out_size, void* d_ws, size_t ws_size,
                              hipStream_t stream)
{
    const float* enc  = (const float*)d_in[1];
    const float* W_ih = (const float*)d_in[2];
    // d_in[3] = W_hh multiplies the always-zero LSTM hidden state -> unused.
    const float* b_ih = (const float*)d_in[4];
    const float* b_hh = (const float*)d_in[5];
    const float* Wq   = (const float*)d_in[6];
    const float* bq   = (const float*)d_in[7];
    const float* Wk   = (const float*)d_in[8];
    const float* bk   = (const float*)d_in[9];

    float* out = (float*)d_out;                       // pointers: 8192*8192
    float* hs  = out + (size_t)T_STEPS * LSEQ;        // hs: 8192*256 (2nd output)

    // ws layout (floats): nw(16) | hstar(256) | Kp(512K) | WTk(16K) |
    //   WTq(16K) | W16v(98304 = 384KB) | cmax(CAP*16) | csum(CAP*16) |
    //   scores(CAP*8192)
    float* wsf   = (float*)d_ws;
    int*   nw_p  = (int*)d_ws;
    float* hstar = wsf + 16;
    float* Kp    = wsf + 16 + 256;
    float* WTk   = Kp + (size_t)LSEQ * D;
    float* WTq   = WTk + 64 * H;
    uint4* W16v  = (uint4*)(WTq + 64 * H);
    size_t off_dyn = 16 + 256 + (size_t)LSEQ * D + 2 * (size_t)64 * H + 24576 * 4;

    size_t wsf_count = ws_size / 4;
    long cap_l = 0;
    if (wsf_count > off_dyn)
        cap_l = (long)((wsf_count - off_dyn) / (LSEQ + 2 * NCH));
    if (cap_l > T_STEPS) cap_l = T_STEPS;
    const int CAP = (int)cap_l;

    float* cmax   = wsf + off_dyn;
    float* csum   = cmax + (size_t)CAP * NCH;
    float* scores = csum + (size_t)CAP * NCH;

    prep_k<<<112, 256, 0, stream>>>(W_ih, Wk, Wq, W16v, WTk, WTq);
    rnn_kp_k<<<257, 512, 0, stream>>>(enc, W16v, b_ih, b_hh, WTk, bk, Kp, hs, hstar, nw_p);
    attnA_fill_k<<<1024, 256, 0, stream>>>(hs, WTq, bq, Kp, hstar, hs, nw_p, CAP, scores, cmax, csum);
    attnCall_k<<<2048, 256, 0, stream>>>(nw_p, CAP, scores, cmax, csum, out);
    if (CAP < T_STEPS)
        attn_fb_k<<<T_STEPS, 256, 0, stream>>>(hs, WTq, bq, Kp, nw_p, CAP, out);
}